// Round 2
// baseline (10394.075 us; speedup 1.0000x reference)
//
#include <hip/hip_runtime.h>
#include <math.h>

#define NN 100000
#define EE 1600000
#define CCH 32
#define NC (NN*CCH)
#define ET (EE+NN)          // edges + self loops
#define NEGS 0.01f
#define GNEG 0.2f
#define BEPS 1e-5f

// ---- order-preserving float<->uint encoding for atomicMax on floats ----
static __device__ __forceinline__ unsigned enc_f(float x){
    unsigned u = __float_as_uint(x);
    return (u & 0x80000000u) ? ~u : (u | 0x80000000u);
}
static __device__ __forceinline__ float dec_f(unsigned e){
    unsigned v = (e & 0x80000000u) ? (e & 0x7FFFFFFFu) : ~e;
    return __uint_as_float(v);
}

// ---------------- degree ----------------
__global__ void k_deg(const int* __restrict__ src, float* __restrict__ deg){
    int e = blockIdx.x*blockDim.x + threadIdx.x;
    if (e < EE) atomicAdd(&deg[src[e]], 1.0f);
}

__global__ void k_w(const int* __restrict__ src, const int* __restrict__ dst,
                    const float* __restrict__ deg, float* __restrict__ wv){
    int e = blockIdx.x*blockDim.x + threadIdx.x;
    if (e >= EE) return;
    float di = deg[src[e]] * deg[dst[e]];
    wv[e] = (di > 0.0f) ? (-1.0f / sqrtf(fmaxf(di, 1e-12f))) : 0.0f;
}

// ---------------- spmv: out[dst] += w * v[src], 8 threads/edge (4 ch each) ----------------
__global__ void k_spmv(const int* __restrict__ src, const int* __restrict__ dst,
                       const float* __restrict__ wv, const float* __restrict__ v,
                       float* __restrict__ out){
    int t = blockIdx.x*blockDim.x + threadIdx.x;
    if (t >= EE*8) return;
    int e = t >> 3, q = t & 7;
    int s = src[e], d = dst[e];
    float we = wv[e];
    float4 vv = *(const float4*)&v[(size_t)s*CCH + q*4];
    float* o = &out[(size_t)d*CCH + q*4];
    atomicAdd(o+0, we*vv.x);
    atomicAdd(o+1, we*vv.y);
    atomicAdd(o+2, we*vv.z);
    atomicAdd(o+3, we*vv.w);
}

// t_new = 2*t_new - t_old  (chebyshev recurrence)
__global__ void k_combine(float* __restrict__ tn, const float* __restrict__ to){
    int i = blockIdx.x*blockDim.x + threadIdx.x;
    if (i < NC) tn[i] = 2.0f*tn[i] - to[i];
}

// ---------------- cheb output GEMM: X[n,:] = sum_k T_k[n,:] @ W[k] + cb ----------------
__global__ void k_cheb(const float* __restrict__ T0, const float* __restrict__ T1,
                       const float* __restrict__ T2, const float* __restrict__ T3,
                       const float* __restrict__ T4,
                       const float* __restrict__ W, const float* __restrict__ cb,
                       int K, float* __restrict__ X){
    __shared__ float sW[5*CCH*CCH];
    for (int i = threadIdx.x; i < K*CCH*CCH; i += blockDim.x) sW[i] = W[i];
    __syncthreads();
    int n = blockIdx.x*blockDim.x + threadIdx.x;
    if (n >= NN) return;
    const float* Ts[5] = {T0, T1, T2, T3, T4};
    float acc[CCH];
    #pragma unroll
    for (int j = 0; j < CCH; j++) acc[j] = cb[j];
    for (int k = 0; k < K; k++){
        const float* tn = &Ts[k][(size_t)n*CCH];
        #pragma unroll 8
        for (int i = 0; i < CCH; i++){
            float t = tn[i];
            const float* wr = &sW[k*CCH*CCH + i*CCH];
            #pragma unroll
            for (int j = 0; j < CCH; j++) acc[j] += t*wr[j];
        }
    }
    float* xo = &X[(size_t)n*CCH];
    #pragma unroll
    for (int j = 0; j < CCH; j++) xo[j] = acc[j];
}

// ---------------- H = X @ G   (G: [32,64]), thread per (node, head) ----------------
__global__ void k_hgemm(const float* __restrict__ X, const float* __restrict__ G,
                        float* __restrict__ Hh){
    __shared__ float sG[CCH*64];
    for (int i = threadIdx.x; i < CCH*64; i += blockDim.x) sG[i] = G[i];
    __syncthreads();
    int t = blockIdx.x*blockDim.x + threadIdx.x;
    if (t >= NN*2) return;
    int n = t >> 1, h = t & 1;
    float acc[CCH];
    #pragma unroll
    for (int j = 0; j < CCH; j++) acc[j] = 0.0f;
    const float* x = &X[(size_t)n*CCH];
    #pragma unroll 8
    for (int i = 0; i < CCH; i++){
        float xv = x[i];
        const float* gr = &sG[i*64 + h*CCH];
        #pragma unroll
        for (int j = 0; j < CCH; j++) acc[j] += xv*gr[j];
    }
    float* o = &Hh[(size_t)n*64 + h*CCH];
    #pragma unroll
    for (int j = 0; j < CCH; j++) o[j] = acc[j];
}

// ---------------- edge attention logits + atomicMax ----------------
__global__ void k_att(const int* __restrict__ src, const int* __restrict__ dst,
                      const float* __restrict__ Hh,
                      const float* __restrict__ al, const float* __restrict__ ar,
                      float* __restrict__ av, unsigned* __restrict__ amax){
    int e = blockIdx.x*blockDim.x + threadIdx.x;
    if (e >= ET) return;
    int s, d;
    if (e < EE){ s = src[e]; d = dst[e]; } else { s = d = e - EE; }
    #pragma unroll
    for (int h = 0; h < 2; h++){
        const float4* hj4 = (const float4*)&Hh[(size_t)s*64 + h*CCH];
        const float4* hi4 = (const float4*)&Hh[(size_t)d*64 + h*CCH];
        const float4* al4 = (const float4*)&al[h*CCH];
        const float4* ar4 = (const float4*)&ar[h*CCH];
        float lg = 0.0f, aj = 0.0f, ai = 0.0f;
        #pragma unroll
        for (int c = 0; c < 8; c++){
            float4 vj = hj4[c], vi = hi4[c], a4 = al4[c], r4 = ar4[c];
            lg += vi.x*vj.x + vi.y*vj.y + vi.z*vj.z + vi.w*vj.w;
            aj += vj.x*a4.x + vj.y*a4.y + vj.z*a4.z + vj.w*a4.w;
            ai += vi.x*r4.x + vi.y*r4.y + vi.z*r4.z + vi.w*r4.w;
        }
        float sg = 1.0f / (1.0f + expf(-lg));
        float v = (aj + ai) * sg;
        float a = (v > 0.0f) ? v : GNEG*v;
        av[(size_t)e*2 + h] = a;
        atomicMax(&amax[(size_t)d*2 + h], enc_f(a));
    }
}

// ---------------- exp + denominator ----------------
__global__ void k_expden(const int* __restrict__ dst, const unsigned* __restrict__ amax,
                         float* __restrict__ av, float* __restrict__ den){
    int t = blockIdx.x*blockDim.x + threadIdx.x;
    if (t >= ET*2) return;
    int e = t >> 1, h = t & 1;
    int d = (e < EE) ? dst[e] : e - EE;
    float m = dec_f(amax[(size_t)d*2 + h]);
    float ex = expf(av[t] - m);
    av[t] = ex;
    atomicAdd(&den[(size_t)d*2 + h], ex);
}

// ---------------- weighted aggregation: gat[d,h,:] += alpha * H[s,h,:] ----------------
__global__ void k_aggr(const int* __restrict__ src, const int* __restrict__ dst,
                       const float* __restrict__ Hh, const float* __restrict__ av,
                       const float* __restrict__ den, float* __restrict__ gat){
    int t = blockIdx.x*blockDim.x + threadIdx.x;
    if (t >= ET*16) return;
    int e = t >> 4, r = t & 15;
    int h = r >> 3, q = r & 7;
    int s, d;
    if (e < EE){ s = src[e]; d = dst[e]; } else { s = d = e - EE; }
    float ex = av[(size_t)e*2 + h];
    float alpha = ex / (den[(size_t)d*2 + h] + 1e-16f);
    float4 hv = *(const float4*)&Hh[(size_t)s*64 + h*CCH + q*4];
    float* o = &gat[(size_t)d*64 + h*CCH + q*4];
    atomicAdd(o+0, alpha*hv.x);
    atomicAdd(o+1, alpha*hv.y);
    atomicAdd(o+2, alpha*hv.z);
    atomicAdd(o+3, alpha*hv.w);
}

// ---------------- y = leaky(s)+s; per-channel sum/sumsq ----------------
__global__ void k_y(const float* __restrict__ gat, const float* __restrict__ gb,
                    float* __restrict__ y, float* __restrict__ sums){
    int t = blockIdx.x*blockDim.x + threadIdx.x;
    int n = t >> 5, c = t & 31;
    float yv = 0.0f;
    if (n < NN){
        float s_ = 0.5f*(gat[(size_t)n*64 + c] + gat[(size_t)n*64 + 32 + c]) + gb[c];
        yv = ((s_ > 0.0f) ? s_ : NEGS*s_) + s_;
        y[(size_t)n*CCH + c] = yv;
    }
    __shared__ float ssum[256], ssq[256];
    ssum[threadIdx.x] = yv;
    ssq[threadIdx.x]  = yv*yv;
    __syncthreads();
    if (threadIdx.x < 32){
        float s = 0.0f, q = 0.0f;
        #pragma unroll
        for (int r = 0; r < 8; r++){
            s += ssum[r*32 + threadIdx.x];
            q += ssq[r*32 + threadIdx.x];
        }
        atomicAdd(&sums[threadIdx.x], s);
        atomicAdd(&sums[32 + threadIdx.x], q);
    }
}

// ---------------- BN normalize + accumulate (mode: 0 store, 1 add, 2 add+final leaky) ----------------
__global__ void k_norm(const float* __restrict__ y, const float* __restrict__ sums,
                       const float* __restrict__ gm, const float* __restrict__ bt,
                       float* __restrict__ acc, int mode){
    int t = blockIdx.x*blockDim.x + threadIdx.x;
    if (t >= NC) return;
    int c = t & 31;
    const float invN = 1.0f / (float)NN;
    float mu = sums[c] * invN;
    float var = sums[32 + c] * invN - mu*mu;
    float inv = 1.0f / sqrtf(var + BEPS);
    float v = gm[c] * (y[t] - mu) * inv + bt[c];
    if (mode == 0){
        acc[t] = v;
    } else if (mode == 1){
        acc[t] += v;
    } else {
        float a = acc[t] + v;
        acc[t] = (a > 0.0f) ? a : NEGS*a;
    }
}

extern "C" void kernel_launch(void* const* d_in, const int* in_sizes, int n_in,
                              void* d_out, int out_size, void* d_ws, size_t ws_size,
                              hipStream_t stream){
    const float* x   = (const float*)d_in[0];
    const int*   ei  = (const int*)d_in[1];
    const int*   src = ei;
    const int*   dst = ei + EE;

    const float *Wp[4], *cbp[4], *Gp[4], *alp[4], *arp[4], *gbp[4], *gmp[4], *btp[4];
    for (int b = 0; b < 4; b++){
        int base = 3 + 8*b;
        Wp[b]  = (const float*)d_in[base+0];
        cbp[b] = (const float*)d_in[base+1];
        Gp[b]  = (const float*)d_in[base+2];
        alp[b] = (const float*)d_in[base+3];
        arp[b] = (const float*)d_in[base+4];
        gbp[b] = (const float*)d_in[base+5];
        gmp[b] = (const float*)d_in[base+6];
        btp[b] = (const float*)d_in[base+7];
    }

    float* ws   = (float*)d_ws;
    float* deg  = ws;           ws += NN;
    float* wv   = ws;           ws += EE;
    float* T1   = ws;           ws += NC;
    float* T2   = ws;           ws += NC;
    float* T3   = ws;           ws += NC;
    float* T4   = ws;           ws += NC;
    float* X    = ws;           ws += NC;
    float* Hh   = ws;           ws += 2*NC;
    float* av   = ws;           ws += 2*ET;
    unsigned* amax = (unsigned*)ws; ws += 2*NN;
    float* den  = ws;           ws += 2*NN;
    float* gat  = ws;           ws += 2*NC;
    float* yb   = ws;           ws += NC;
    float* sums = ws;           ws += 64;

    float* acc = (float*)d_out;   // accumulate blocks directly into the output buffer

    const int B = 256;
    const int gE    = (EE + B - 1)/B;
    const int gE8   = (EE*8 + B - 1)/B;
    const int gNC   = (NC + B - 1)/B;
    const int gN    = (NN + B - 1)/B;
    const int gN2   = (NN*2 + B - 1)/B;
    const int gET   = (ET + B - 1)/B;
    const int gET2  = (ET*2 + B - 1)/B;
    const int gET16 = (ET*16 + B - 1)/B;

    // degree + weights
    hipMemsetAsync(deg, 0, NN*sizeof(float), stream);
    k_deg<<<gE, B, 0, stream>>>(src, deg);
    k_w<<<gE, B, 0, stream>>>(src, dst, deg, wv);

    // Chebyshev basis (shared across all 4 blocks)
    hipMemsetAsync(T1, 0, NC*sizeof(float), stream);
    k_spmv<<<gE8, B, 0, stream>>>(src, dst, wv, x, T1);
    hipMemsetAsync(T2, 0, NC*sizeof(float), stream);
    k_spmv<<<gE8, B, 0, stream>>>(src, dst, wv, T1, T2);
    k_combine<<<gNC, B, 0, stream>>>(T2, x);
    hipMemsetAsync(T3, 0, NC*sizeof(float), stream);
    k_spmv<<<gE8, B, 0, stream>>>(src, dst, wv, T2, T3);
    k_combine<<<gNC, B, 0, stream>>>(T3, T1);
    hipMemsetAsync(T4, 0, NC*sizeof(float), stream);
    k_spmv<<<gE8, B, 0, stream>>>(src, dst, wv, T3, T4);
    k_combine<<<gNC, B, 0, stream>>>(T4, T2);

    const int Ks[4] = {3, 3, 5, 5};
    for (int b = 0; b < 4; b++){
        k_cheb<<<gN, B, 0, stream>>>(x, T1, T2, T3, T4, Wp[b], cbp[b], Ks[b], X);
        k_hgemm<<<gN2, B, 0, stream>>>(X, Gp[b], Hh);

        hipMemsetAsync(amax, 0, 2*NN*sizeof(unsigned), stream);  // 0 == encoded(-NaN), below all reals
        hipMemsetAsync(den,  0, 2*NN*sizeof(float), stream);
        hipMemsetAsync(gat,  0, 2*NC*sizeof(float), stream);
        hipMemsetAsync(sums, 0, 64*sizeof(float), stream);

        k_att<<<gET, B, 0, stream>>>(src, dst, Hh, alp[b], arp[b], av, amax);
        k_expden<<<gET2, B, 0, stream>>>(dst, amax, av, den);
        k_aggr<<<gET16, B, 0, stream>>>(src, dst, Hh, av, den, gat);
        k_y<<<(NN*32 + B - 1)/B, B, 0, stream>>>(gat, gbp[b], yb, sums);
        int mode = (b == 0) ? 0 : ((b == 3) ? 2 : 1);
        k_norm<<<gNC, B, 0, stream>>>(yb, sums, gmp[b], btp[b], acc, mode);
    }
}

// Round 3
// 5451.162 us; speedup vs baseline: 1.9068x; 1.9068x over previous
//
#include <hip/hip_runtime.h>
#include <math.h>

#define NN 100000
#define EE 1600000
#define CCH 32
#define NC (NN*CCH)
#define ET (EE+NN)          // edges + self loops (one per node)
#define NEGS 0.01f
#define GNEG 0.2f
#define BEPS 1e-5f

// ============ CSR build ============

// out-degree (float, for edge weights) + in-degree (int, for CSR rows)
__global__ void k_degs(const int* __restrict__ src, const int* __restrict__ dst,
                       float* __restrict__ deg_out, int* __restrict__ indeg){
    int e = blockIdx.x*blockDim.x + threadIdx.x;
    if (e >= EE) return;
    atomicAdd(&deg_out[src[e]], 1.0f);
    atomicAdd(&indeg[dst[e]], 1);
}

// single-block exclusive scan of (indeg[d]+1) -> row[0..NN]
#define SCAN_T 1024
__global__ void k_scan(const int* __restrict__ indeg, int* __restrict__ row){
    __shared__ int sdata[SCAN_T];
    int t = threadIdx.x;
    const int per = (NN + SCAN_T - 1)/SCAN_T;
    int lo = t*per, hi = (lo + per < NN) ? lo + per : NN;
    int s = 0;
    for (int d = lo; d < hi; d++) s += indeg[d] + 1;
    sdata[t] = s;
    __syncthreads();
    for (int off = 1; off < SCAN_T; off <<= 1){
        int v = (t >= off) ? sdata[t-off] : 0;
        __syncthreads();
        sdata[t] += v;
        __syncthreads();
    }
    int excl = (t == 0) ? 0 : sdata[t-1];
    for (int d = lo; d < hi; d++){
        row[d] = excl;
        excl += indeg[d] + 1;
    }
    if (t == 0) row[NN] = ET;
}

// self-loop occupies slot 0 of each segment
__global__ void k_self(const int* __restrict__ row, int* __restrict__ csr_src,
                       float* __restrict__ csr_w){
    int d = blockIdx.x*blockDim.x + threadIdx.x;
    if (d >= NN) return;
    int p = row[d];
    csr_src[p] = d;
    csr_w[p] = 0.0f;
}

// scatter edges into CSR slots [row[d]+1 ...], fuse weight computation
__global__ void k_scatter(const int* __restrict__ src, const int* __restrict__ dst,
                          const float* __restrict__ deg_out, const int* __restrict__ row,
                          int* __restrict__ cur, int* __restrict__ csr_src,
                          float* __restrict__ csr_w){
    int e = blockIdx.x*blockDim.x + threadIdx.x;
    if (e >= EE) return;
    int s = src[e], d = dst[e];
    int pos = row[d] + 1 + atomicAdd(&cur[d], 1);
    csr_src[pos] = s;
    float di = deg_out[s] * deg_out[d];
    csr_w[pos] = (di > 0.0f) ? (-1.0f / sqrtf(fmaxf(di, 1e-12f))) : 0.0f;
}

// ============ gather SpMV with fused Chebyshev combine ============
// one wave per node: 64 lanes = 2 edge-slots x 32 channels. no atomics.
__global__ void k_spmv_csr(const int* __restrict__ row, const int* __restrict__ csr_src,
                           const float* __restrict__ csr_w, const float* __restrict__ v,
                           const float* __restrict__ tprev, float* __restrict__ out, int first){
    int gid = blockIdx.x*blockDim.x + threadIdx.x;
    int node = gid >> 6;
    if (node >= NN) return;
    int lane = gid & 63;
    int slot = lane >> 5, c = lane & 31;
    int start = row[node] + 1, end = row[node+1];   // skip self-loop slot
    float acc = 0.0f;
    for (int p = start + slot; p < end; p += 2){
        int s = csr_src[p];
        acc += csr_w[p] * v[(size_t)s*CCH + c];
    }
    acc += __shfl_xor(acc, 32);
    if (slot == 0){
        float r = first ? acc : 2.0f*acc - tprev[(size_t)node*CCH + c];
        out[(size_t)node*CCH + c] = r;
    }
}

// ============ Wg_k = W_k @ G, cbg = cb @ G (tiny) ============
__global__ void k_wg(const float* __restrict__ W, const float* __restrict__ cb,
                     const float* __restrict__ G, float* __restrict__ Wg,
                     float* __restrict__ cbg, int K){
    int t = blockIdx.x*blockDim.x + threadIdx.x;
    if (t < K*2048){
        int k = t >> 11, r = t & 2047;
        int i = r >> 6, j = r & 63;
        float s = 0.0f;
        #pragma unroll 8
        for (int q = 0; q < 32; q++) s += W[k*1024 + i*32 + q] * G[q*64 + j];
        Wg[t] = s;
    } else if (t < K*2048 + 64){
        int j = t - K*2048;
        float s = 0.0f;
        #pragma unroll 8
        for (int q = 0; q < 32; q++) s += cb[q] * G[q*64 + j];
        cbg[j] = s;
    }
}

// ============ H = (sum_k T_k @ Wg_k) + cbg, one wave per node ============
__global__ void k_hfused(const float* __restrict__ T0, const float* __restrict__ T1,
                         const float* __restrict__ T2, const float* __restrict__ T3,
                         const float* __restrict__ T4,
                         const float* __restrict__ Wg, const float* __restrict__ cbg,
                         int K, float* __restrict__ Hh){
    __shared__ float sW[5*2048];
    for (int i = threadIdx.x; i < K*2048; i += blockDim.x) sW[i] = Wg[i];
    __syncthreads();
    int gid = blockIdx.x*blockDim.x + threadIdx.x;
    int node = gid >> 6;
    if (node >= NN) return;
    int lane = gid & 63;
    const float* Ts[5] = {T0, T1, T2, T3, T4};
    float acc = cbg[lane];
    for (int k = 0; k < K; k++){
        float tv = Ts[k][(size_t)node*CCH + (lane & 31)];   // lanes 0..31 hold the row
        const float* wrow = &sW[k*2048];
        #pragma unroll
        for (int i = 0; i < 32; i++){
            float t = __shfl(tv, i);
            acc += t * wrow[i*64 + lane];
        }
    }
    Hh[(size_t)node*64 + lane] = acc;
}

// ============ fused SuperGAT: logits + max + softmax + aggregate + y + BN sums ============
// one wave per dst node: 64 lanes = 2 heads x 32 channels
__global__ void k_gat(const int* __restrict__ row, const int* __restrict__ csr_src,
                      const float* __restrict__ Hh,
                      const float* __restrict__ al, const float* __restrict__ ar,
                      const float* __restrict__ gb,
                      float* __restrict__ av, float* __restrict__ y,
                      float* __restrict__ sums){
    int gid = blockIdx.x*blockDim.x + threadIdx.x;
    int node = gid >> 6;
    int lane = gid & 63;
    int wv_ = threadIdx.x >> 6;
    int h = lane >> 5, c = lane & 31;
    __shared__ float ssum[4*32], ssq[4*32];
    float yv = 0.0f;
    if (node < NN){
        float hi = Hh[(size_t)node*64 + lane];
        float alv = al[h*32 + c], arv = ar[h*32 + c];
        float ai = hi * arv;
        #pragma unroll
        for (int m = 16; m >= 1; m >>= 1) ai += __shfl_xor(ai, m);
        int start = row[node], end = row[node+1];
        // pass 1: attention logits, running max; park a_e in global scratch
        float mx = -1e30f;
        for (int p = start; p < end; p++){
            int s = csr_src[p];
            float hj = Hh[(size_t)s*64 + lane];
            float lg = hi*hj, aj = hj*alv;
            #pragma unroll
            for (int m = 16; m >= 1; m >>= 1){
                lg += __shfl_xor(lg, m);
                aj += __shfl_xor(aj, m);
            }
            float sg = 1.0f / (1.0f + expf(-lg));
            float a = (aj + ai) * sg;
            a = (a > 0.0f) ? a : GNEG*a;
            if (c == 0) av[(size_t)p*2 + h] = a;
            mx = fmaxf(mx, a);
        }
        __threadfence_block();
        // pass 2: denominator
        float den = 0.0f;
        for (int p = start; p < end; p++) den += expf(av[(size_t)p*2 + h] - mx);
        den += 1e-16f;
        // pass 3: weighted aggregation
        float acc = 0.0f;
        for (int p = start; p < end; p++){
            int s = csr_src[p];
            float alpha = expf(av[(size_t)p*2 + h] - mx) / den;
            acc += alpha * Hh[(size_t)s*64 + lane];
        }
        float s_ = 0.5f*(acc + __shfl_xor(acc, 32)) + gb[c];
        yv = (s_ > 0.0f) ? 2.0f*s_ : (1.0f + NEGS)*s_;   // leaky(s)+s
        if (h == 0) y[(size_t)node*CCH + c] = yv;
    }
    // block-level BN partial sums (value identical across the two head halves; use h==0)
    if (h == 0){
        ssum[wv_*32 + c] = (node < NN) ? yv : 0.0f;
        ssq[wv_*32 + c]  = (node < NN) ? yv*yv : 0.0f;
    }
    __syncthreads();
    if (threadIdx.x < 32){
        float s = 0.0f, q = 0.0f;
        #pragma unroll
        for (int r = 0; r < 4; r++){
            s += ssum[r*32 + threadIdx.x];
            q += ssq[r*32 + threadIdx.x];
        }
        atomicAdd(&sums[threadIdx.x], s);
        atomicAdd(&sums[32 + threadIdx.x], q);
    }
}

// ============ BN normalize + accumulate (0 store, 1 add, 2 add+final leaky) ============
__global__ void k_norm(const float* __restrict__ y, const float* __restrict__ sums,
                       const float* __restrict__ gm, const float* __restrict__ bt,
                       float* __restrict__ acc, int mode){
    int t = blockIdx.x*blockDim.x + threadIdx.x;
    if (t >= NC) return;
    int c = t & 31;
    const float invN = 1.0f / (float)NN;
    float mu = sums[c] * invN;
    float var = sums[32 + c] * invN - mu*mu;
    float inv = 1.0f / sqrtf(var + BEPS);
    float v = gm[c] * (y[t] - mu) * inv + bt[c];
    if (mode == 0){
        acc[t] = v;
    } else if (mode == 1){
        acc[t] += v;
    } else {
        float a = acc[t] + v;
        acc[t] = (a > 0.0f) ? a : NEGS*a;
    }
}

extern "C" void kernel_launch(void* const* d_in, const int* in_sizes, int n_in,
                              void* d_out, int out_size, void* d_ws, size_t ws_size,
                              hipStream_t stream){
    const float* x   = (const float*)d_in[0];
    const int*   ei  = (const int*)d_in[1];
    const int*   src = ei;
    const int*   dst = ei + EE;

    const float *Wp[4], *cbp[4], *Gp[4], *alp[4], *arp[4], *gbp[4], *gmp[4], *btp[4];
    for (int b = 0; b < 4; b++){
        int base = 3 + 8*b;
        Wp[b]  = (const float*)d_in[base+0];
        cbp[b] = (const float*)d_in[base+1];
        Gp[b]  = (const float*)d_in[base+2];
        alp[b] = (const float*)d_in[base+3];
        arp[b] = (const float*)d_in[base+4];
        gbp[b] = (const float*)d_in[base+5];
        gmp[b] = (const float*)d_in[base+6];
        btp[b] = (const float*)d_in[base+7];
    }

    char* w8 = (char*)d_ws;
    float* deg_out = (float*)w8;            w8 += sizeof(float)*NN;
    int*   indeg   = (int*)w8;              w8 += sizeof(int)*NN;
    int*   cur     = (int*)w8;              w8 += sizeof(int)*NN;
    int*   row     = (int*)w8;              w8 += sizeof(int)*(NN+1);
    int*   csr_src = (int*)w8;              w8 += sizeof(int)*ET;
    float* csr_w   = (float*)w8;            w8 += sizeof(float)*ET;
    float* T1      = (float*)w8;            w8 += sizeof(float)*NC;
    float* T2      = (float*)w8;            w8 += sizeof(float)*NC;
    float* T3      = (float*)w8;            w8 += sizeof(float)*NC;
    float* T4      = (float*)w8;            w8 += sizeof(float)*NC;
    float* Hh      = (float*)w8;            w8 += sizeof(float)*2*NC;
    float* av      = (float*)w8;            w8 += sizeof(float)*2*ET;
    float* yb      = (float*)w8;            w8 += sizeof(float)*NC;
    float* Wg      = (float*)w8;            w8 += sizeof(float)*4*5*2048;
    float* cbg     = (float*)w8;            w8 += sizeof(float)*4*64;
    float* sums    = (float*)w8;            w8 += sizeof(float)*64;

    float* acc = (float*)d_out;

    const int B = 256;
    const int gE  = (EE + B - 1)/B;
    const int gN  = (NN + B - 1)/B;
    const int gNC = (NC + B - 1)/B;
    const int gW  = (NN*64 + B - 1)/B;   // one wave per node kernels

    // ---- CSR build ----
    hipMemsetAsync(deg_out, 0, (size_t)3*NN*sizeof(int), stream);  // deg_out, indeg, cur (contiguous)
    k_degs<<<gE, B, 0, stream>>>(src, dst, deg_out, indeg);
    k_scan<<<1, SCAN_T, 0, stream>>>(indeg, row);
    k_self<<<gN, B, 0, stream>>>(row, csr_src, csr_w);
    k_scatter<<<gE, B, 0, stream>>>(src, dst, deg_out, row, cur, csr_src, csr_w);

    // ---- shared Chebyshev basis (gather SpMV, fused recurrence) ----
    k_spmv_csr<<<gW, B, 0, stream>>>(row, csr_src, csr_w, x,  (const float*)0, T1, 1);
    k_spmv_csr<<<gW, B, 0, stream>>>(row, csr_src, csr_w, T1, x,  T2, 0);
    k_spmv_csr<<<gW, B, 0, stream>>>(row, csr_src, csr_w, T2, T1, T3, 0);
    k_spmv_csr<<<gW, B, 0, stream>>>(row, csr_src, csr_w, T3, T2, T4, 0);

    // ---- per-block folded weights ----
    const int Ks[4] = {3, 3, 5, 5};
    for (int b = 0; b < 4; b++){
        int tot = Ks[b]*2048 + 64;
        k_wg<<<(tot + B - 1)/B, B, 0, stream>>>(Wp[b], cbp[b], Gp[b],
                                                Wg + b*5*2048, cbg + b*64, Ks[b]);
    }

    // ---- per-block pipeline ----
    for (int b = 0; b < 4; b++){
        k_hfused<<<gW, B, 0, stream>>>(x, T1, T2, T3, T4, Wg + b*5*2048, cbg + b*64,
                                       Ks[b], Hh);
        hipMemsetAsync(sums, 0, 64*sizeof(float), stream);
        k_gat<<<gW, B, 0, stream>>>(row, csr_src, Hh, alp[b], arp[b], gbp[b],
                                    av, yb, sums);
        int mode = (b == 0) ? 0 : ((b == 3) ? 2 : 1);
        k_norm<<<gNC, B, 0, stream>>>(yb, sums, gmp[b], btp[b], acc, mode);
    }
}

// Round 4
// 3635.197 us; speedup vs baseline: 2.8593x; 1.4996x over previous
//
#include <hip/hip_runtime.h>
#include <math.h>

#define NN 100000
#define EE 1600000
#define CCH 32
#define NC (NN*CCH)
#define ET (EE+NN)          // edges + self loops (one per node)
#define NEGS 0.01f
#define GNEG 0.2f
#define BEPS 1e-5f

// ============ CSR build ============

__global__ void k_degs(const int* __restrict__ src, const int* __restrict__ dst,
                       float* __restrict__ deg_out, int* __restrict__ indeg){
    int e = blockIdx.x*blockDim.x + threadIdx.x;
    if (e >= EE) return;
    atomicAdd(&deg_out[src[e]], 1.0f);
    atomicAdd(&indeg[dst[e]], 1);
}

#define SCAN_T 1024
__global__ void k_scan(const int* __restrict__ indeg, int* __restrict__ row){
    __shared__ int sdata[SCAN_T];
    int t = threadIdx.x;
    const int per = (NN + SCAN_T - 1)/SCAN_T;
    int lo = t*per, hi = (lo + per < NN) ? lo + per : NN;
    int s = 0;
    for (int d = lo; d < hi; d++) s += indeg[d] + 1;
    sdata[t] = s;
    __syncthreads();
    for (int off = 1; off < SCAN_T; off <<= 1){
        int v = (t >= off) ? sdata[t-off] : 0;
        __syncthreads();
        sdata[t] += v;
        __syncthreads();
    }
    int excl = (t == 0) ? 0 : sdata[t-1];
    for (int d = lo; d < hi; d++){
        row[d] = excl;
        excl += indeg[d] + 1;
    }
    if (t == 0) row[NN] = ET;
}

__global__ void k_self(const int* __restrict__ row, int* __restrict__ csr_src,
                       float* __restrict__ csr_w){
    int d = blockIdx.x*blockDim.x + threadIdx.x;
    if (d >= NN) return;
    int p = row[d];
    csr_src[p] = d;
    csr_w[p] = 0.0f;
}

__global__ void k_scatter(const int* __restrict__ src, const int* __restrict__ dst,
                          const float* __restrict__ deg_out, const int* __restrict__ row,
                          int* __restrict__ cur, int* __restrict__ csr_src,
                          float* __restrict__ csr_w){
    int e = blockIdx.x*blockDim.x + threadIdx.x;
    if (e >= EE) return;
    int s = src[e], d = dst[e];
    int pos = row[d] + 1 + atomicAdd(&cur[d], 1);
    csr_src[pos] = s;
    float di = deg_out[s] * deg_out[d];
    csr_w[pos] = (di > 0.0f) ? (-1.0f / sqrtf(fmaxf(di, 1e-12f))) : 0.0f;
}

// ============ gather SpMV, fused Chebyshev combine, unroll x2 ============
// one wave per node: 64 lanes = 2 edge-slots x 32 channels
__global__ void k_spmv_csr(const int* __restrict__ row, const int* __restrict__ csr_src,
                           const float* __restrict__ csr_w, const float* __restrict__ v,
                           const float* __restrict__ tprev, float* __restrict__ out, int first){
    int gid = blockIdx.x*blockDim.x + threadIdx.x;
    int node = gid >> 6;
    if (node >= NN) return;
    int lane = gid & 63;
    int slot = lane >> 5, c = lane & 31;
    int start = row[node] + 1, end = row[node+1];   // skip self-loop slot
    float acc = 0.0f;
    int p = start + slot;
    for (; p + 2 < end; p += 4){
        int s0 = csr_src[p], s1 = csr_src[p+2];
        float w0 = csr_w[p], w1 = csr_w[p+2];
        acc += w0 * v[(size_t)s0*CCH + c] + w1 * v[(size_t)s1*CCH + c];
    }
    if (p < end){
        acc += csr_w[p] * v[(size_t)csr_src[p]*CCH + c];
    }
    acc += __shfl_xor(acc, 32);
    if (slot == 0){
        float r = first ? acc : 2.0f*acc - tprev[(size_t)node*CCH + c];
        out[(size_t)node*CCH + c] = r;
    }
}

// ============ Wg_k = W_k @ G, cbg = cb @ G (tiny) ============
__global__ void k_wg(const float* __restrict__ W, const float* __restrict__ cb,
                     const float* __restrict__ G, float* __restrict__ Wg,
                     float* __restrict__ cbg, int K){
    int t = blockIdx.x*blockDim.x + threadIdx.x;
    if (t < K*2048){
        int k = t >> 11, r = t & 2047;
        int i = r >> 6, j = r & 63;
        float s = 0.0f;
        #pragma unroll 8
        for (int q = 0; q < 32; q++) s += W[k*1024 + i*32 + q] * G[q*64 + j];
        Wg[t] = s;
    } else if (t < K*2048 + 64){
        int j = t - K*2048;
        float s = 0.0f;
        #pragma unroll 8
        for (int q = 0; q < 32; q++) s += cb[q] * G[q*64 + j];
        cbg[j] = s;
    }
}

// ============ H = (sum_k T_k @ Wg_k) + cbg; also attL/attR dots ============
__global__ void k_hfused(const float* __restrict__ T0, const float* __restrict__ T1,
                         const float* __restrict__ T2, const float* __restrict__ T3,
                         const float* __restrict__ T4,
                         const float* __restrict__ Wg, const float* __restrict__ cbg,
                         const float* __restrict__ al, const float* __restrict__ ar,
                         int K, float* __restrict__ Hh,
                         float* __restrict__ attL, float* __restrict__ attR){
    __shared__ float sW[5*2048];
    for (int i = threadIdx.x; i < K*2048; i += blockDim.x) sW[i] = Wg[i];
    __syncthreads();
    int gid = blockIdx.x*blockDim.x + threadIdx.x;
    int node = gid >> 6;
    if (node >= NN) return;
    int lane = gid & 63;
    int h = lane >> 5, c = lane & 31;
    const float* Ts[5] = {T0, T1, T2, T3, T4};
    float acc = cbg[lane];
    for (int k = 0; k < K; k++){
        float tv = Ts[k][(size_t)node*CCH + c];   // lanes 0..31 hold the row (both halves load same)
        const float* wrow = &sW[k*2048];
        #pragma unroll
        for (int i = 0; i < 32; i++){
            float t = __shfl(tv, i);
            acc += t * wrow[i*64 + lane];
        }
    }
    Hh[(size_t)node*64 + lane] = acc;
    // attention dot products: al/ar are [2][32] = 64 floats, lane-mapped
    float va = acc * al[lane];
    float vr = acc * ar[lane];
    #pragma unroll
    for (int m = 16; m >= 1; m >>= 1){
        va += __shfl_xor(va, m);
        vr += __shfl_xor(vr, m);
    }
    if (c == 0){
        attL[(size_t)node*2 + h] = va;
        attR[(size_t)node*2 + h] = vr;
    }
}

// ============ fused SuperGAT, single pass (online softmax) ============
// one wave per dst node: 64 lanes = 2 heads x 32 channels; block = 512 (8 waves)
__global__ void k_gat(const int* __restrict__ row, const int* __restrict__ csr_src,
                      const float* __restrict__ Hh,
                      const float* __restrict__ attL, const float* __restrict__ attR,
                      const float* __restrict__ gb,
                      float* __restrict__ y, float* __restrict__ sums){
    int gid = blockIdx.x*blockDim.x + threadIdx.x;
    int node = gid >> 6;
    int lane = gid & 63;
    int wv_ = threadIdx.x >> 6;
    int h = lane >> 5, c = lane & 31;
    __shared__ float ssum[8*32], ssq[8*32];
    float yv = 0.0f;
    if (node < NN){
        float hi = Hh[(size_t)node*64 + lane];
        float ai = attR[(size_t)node*2 + h];
        int start = row[node], end = row[node+1];
        float m = -1e30f, den = 0.0f, acc = 0.0f;
        int p = start;
        for (; p + 1 < end; p += 2){
            int s0 = csr_src[p], s1 = csr_src[p+1];
            float hj0 = Hh[(size_t)s0*64 + lane];
            float hj1 = Hh[(size_t)s1*64 + lane];
            float aL0 = attL[(size_t)s0*2 + h];
            float aL1 = attL[(size_t)s1*2 + h];
            float lg0 = hi*hj0, lg1 = hi*hj1;
            #pragma unroll
            for (int mm = 16; mm >= 1; mm >>= 1){
                lg0 += __shfl_xor(lg0, mm);
                lg1 += __shfl_xor(lg1, mm);
            }
            float a0 = (aL0 + ai) / (1.0f + __expf(-lg0));
            float a1 = (aL1 + ai) / (1.0f + __expf(-lg1));
            a0 = (a0 > 0.0f) ? a0 : GNEG*a0;
            a1 = (a1 > 0.0f) ? a1 : GNEG*a1;
            float mn = fmaxf(fmaxf(m, a0), a1);        // v_max3
            float sc = __expf(m - mn);
            float w0 = __expf(a0 - mn);
            float w1 = __expf(a1 - mn);
            den = den*sc + w0 + w1;
            acc = acc*sc + w0*hj0 + w1*hj1;
            m = mn;
        }
        if (p < end){
            int s0 = csr_src[p];
            float hj0 = Hh[(size_t)s0*64 + lane];
            float aL0 = attL[(size_t)s0*2 + h];
            float lg0 = hi*hj0;
            #pragma unroll
            for (int mm = 16; mm >= 1; mm >>= 1) lg0 += __shfl_xor(lg0, mm);
            float a0 = (aL0 + ai) / (1.0f + __expf(-lg0));
            a0 = (a0 > 0.0f) ? a0 : GNEG*a0;
            float mn = fmaxf(m, a0);
            float sc = __expf(m - mn);
            float w0 = __expf(a0 - mn);
            den = den*sc + w0;
            acc = acc*sc + w0*hj0;
        }
        float accn = acc / (den + 1e-16f);
        float s_ = 0.5f*(accn + __shfl_xor(accn, 32)) + gb[c];
        yv = (s_ > 0.0f) ? 2.0f*s_ : (1.0f + NEGS)*s_;   // leaky(s)+s
        if (h == 0) y[(size_t)node*CCH + c] = yv;
    }
    if (h == 0){
        ssum[wv_*32 + c] = (node < NN) ? yv : 0.0f;
        ssq[wv_*32 + c]  = (node < NN) ? yv*yv : 0.0f;
    }
    __syncthreads();
    if (threadIdx.x < 32){
        float s = 0.0f, q = 0.0f;
        #pragma unroll
        for (int r = 0; r < 8; r++){
            s += ssum[r*32 + threadIdx.x];
            q += ssq[r*32 + threadIdx.x];
        }
        atomicAdd(&sums[threadIdx.x], s);
        atomicAdd(&sums[32 + threadIdx.x], q);
    }
}

// ============ BN normalize + accumulate (0 store, 1 add, 2 add+final leaky) ============
__global__ void k_norm(const float* __restrict__ y, const float* __restrict__ sums,
                       const float* __restrict__ gm, const float* __restrict__ bt,
                       float* __restrict__ acc, int mode){
    int t = blockIdx.x*blockDim.x + threadIdx.x;
    if (t >= NC) return;
    int c = t & 31;
    const float invN = 1.0f / (float)NN;
    float mu = sums[c] * invN;
    float var = sums[32 + c] * invN - mu*mu;
    float inv = 1.0f / sqrtf(var + BEPS);
    float v = gm[c] * (y[t] - mu) * inv + bt[c];
    if (mode == 0){
        acc[t] = v;
    } else if (mode == 1){
        acc[t] += v;
    } else {
        float a = acc[t] + v;
        acc[t] = (a > 0.0f) ? a : NEGS*a;
    }
}

extern "C" void kernel_launch(void* const* d_in, const int* in_sizes, int n_in,
                              void* d_out, int out_size, void* d_ws, size_t ws_size,
                              hipStream_t stream){
    const float* x   = (const float*)d_in[0];
    const int*   ei  = (const int*)d_in[1];
    const int*   src = ei;
    const int*   dst = ei + EE;

    const float *Wp[4], *cbp[4], *Gp[4], *alp[4], *arp[4], *gbp[4], *gmp[4], *btp[4];
    for (int b = 0; b < 4; b++){
        int base = 3 + 8*b;
        Wp[b]  = (const float*)d_in[base+0];
        cbp[b] = (const float*)d_in[base+1];
        Gp[b]  = (const float*)d_in[base+2];
        alp[b] = (const float*)d_in[base+3];
        arp[b] = (const float*)d_in[base+4];
        gbp[b] = (const float*)d_in[base+5];
        gmp[b] = (const float*)d_in[base+6];
        btp[b] = (const float*)d_in[base+7];
    }

    char* w8 = (char*)d_ws;
    float* deg_out = (float*)w8;            w8 += sizeof(float)*NN;
    int*   indeg   = (int*)w8;              w8 += sizeof(int)*NN;
    int*   cur     = (int*)w8;              w8 += sizeof(int)*NN;
    int*   row     = (int*)w8;              w8 += sizeof(int)*(NN+1);
    int*   csr_src = (int*)w8;              w8 += sizeof(int)*ET;
    float* csr_w   = (float*)w8;            w8 += sizeof(float)*ET;
    float* T1      = (float*)w8;            w8 += sizeof(float)*NC;
    float* T2      = (float*)w8;            w8 += sizeof(float)*NC;
    float* T3      = (float*)w8;            w8 += sizeof(float)*NC;
    float* T4      = (float*)w8;            w8 += sizeof(float)*NC;
    float* Hh      = (float*)w8;            w8 += sizeof(float)*2*NC;
    float* attL    = (float*)w8;            w8 += sizeof(float)*2*NN;
    float* attR    = (float*)w8;            w8 += sizeof(float)*2*NN;
    float* yb      = (float*)w8;            w8 += sizeof(float)*NC;
    float* Wg      = (float*)w8;            w8 += sizeof(float)*4*5*2048;
    float* cbg     = (float*)w8;            w8 += sizeof(float)*4*64;
    float* sums    = (float*)w8;            w8 += sizeof(float)*64;

    float* acc = (float*)d_out;

    const int B = 256;
    const int gE  = (EE + B - 1)/B;
    const int gN  = (NN + B - 1)/B;
    const int gNC = (NC + B - 1)/B;
    const int gW  = (NN*64 + B - 1)/B;      // one-wave-per-node kernels @256
    const int gW5 = (NN*64 + 511)/512;      // one-wave-per-node @512

    // ---- CSR build ----
    hipMemsetAsync(deg_out, 0, (size_t)3*NN*sizeof(int), stream);  // deg_out, indeg, cur
    k_degs<<<gE, B, 0, stream>>>(src, dst, deg_out, indeg);
    k_scan<<<1, SCAN_T, 0, stream>>>(indeg, row);
    k_self<<<gN, B, 0, stream>>>(row, csr_src, csr_w);
    k_scatter<<<gE, B, 0, stream>>>(src, dst, deg_out, row, cur, csr_src, csr_w);

    // ---- shared Chebyshev basis ----
    k_spmv_csr<<<gW, B, 0, stream>>>(row, csr_src, csr_w, x,  (const float*)0, T1, 1);
    k_spmv_csr<<<gW, B, 0, stream>>>(row, csr_src, csr_w, T1, x,  T2, 0);
    k_spmv_csr<<<gW, B, 0, stream>>>(row, csr_src, csr_w, T2, T1, T3, 0);
    k_spmv_csr<<<gW, B, 0, stream>>>(row, csr_src, csr_w, T3, T2, T4, 0);

    // ---- per-block folded weights ----
    const int Ks[4] = {3, 3, 5, 5};
    for (int b = 0; b < 4; b++){
        int tot = Ks[b]*2048 + 64;
        k_wg<<<(tot + B - 1)/B, B, 0, stream>>>(Wp[b], cbp[b], Gp[b],
                                                Wg + b*5*2048, cbg + b*64, Ks[b]);
    }

    // ---- per-block pipeline ----
    for (int b = 0; b < 4; b++){
        k_hfused<<<gW, B, 0, stream>>>(x, T1, T2, T3, T4, Wg + b*5*2048, cbg + b*64,
                                       alp[b], arp[b], Ks[b], Hh, attL, attR);
        hipMemsetAsync(sums, 0, 64*sizeof(float), stream);
        k_gat<<<gW5, 512, 0, stream>>>(row, csr_src, Hh, attL, attR, gbp[b],
                                       yb, sums);
        int mode = (b == 0) ? 0 : ((b == 3) ? 2 : 1);
        k_norm<<<gNC, B, 0, stream>>>(yb, sums, gmp[b], btp[b], acc, mode);
    }
}